// Round 4
// baseline (358.391 us; speedup 1.0000x reference)
//
#include <hip/hip_runtime.h>

#define H 4096
#define THREADS 256

__device__ __forceinline__ float dot4(float4 a, float4 b) {
    return a.x * b.x + a.y * b.y + a.z * b.z + a.w * b.w;
}

// ---------- kernel 0: C[rp][r] = sum_d A_v[rp][d] * B_q[d][r]  (4x4) ----------
__global__ void __launch_bounds__(THREADS) compute_C_kernel(
    const float* __restrict__ A_v, const float* __restrict__ B_q,
    float* __restrict__ C)
{
    const int tid = threadIdx.x;
    float acc[4][4];
#pragma unroll
    for (int i = 0; i < 4; ++i)
#pragma unroll
        for (int j = 0; j < 4; ++j) acc[i][j] = 0.f;

#pragma unroll
    for (int c = 0; c < 4; ++c) {
        const int d0 = c * (THREADS * 4) + tid * 4;
        float avf[4][4], bqf[4][4];
#pragma unroll
        for (int r = 0; r < 4; ++r) {
            float4 t = *reinterpret_cast<const float4*>(A_v + (size_t)r * H + d0);
            avf[r][0] = t.x; avf[r][1] = t.y; avf[r][2] = t.z; avf[r][3] = t.w;
        }
#pragma unroll
        for (int i = 0; i < 4; ++i) {
            float4 t = *reinterpret_cast<const float4*>(B_q + (size_t)(d0 + i) * 4);
            bqf[i][0] = t.x; bqf[i][1] = t.y; bqf[i][2] = t.z; bqf[i][3] = t.w;
        }
#pragma unroll
        for (int i = 0; i < 4; ++i)
#pragma unroll
            for (int rp = 0; rp < 4; ++rp)
#pragma unroll
                for (int r = 0; r < 4; ++r)
                    acc[rp][r] += avf[rp][i] * bqf[i][r];
    }

    const int lane = tid & 63, wave = tid >> 6;
    __shared__ float red[4][16];
#pragma unroll
    for (int rp = 0; rp < 4; ++rp)
#pragma unroll
        for (int r = 0; r < 4; ++r) {
            float v = acc[rp][r];
#pragma unroll
            for (int off = 32; off; off >>= 1) v += __shfl_down(v, off, 64);
            if (lane == 0) red[wave][rp * 4 + r] = v;
        }
    __syncthreads();
    if (tid < 16) C[tid] = red[0][tid] + red[1][tid] + red[2][tid] + red[3][tid];
}

// ---------- kernel 1: per-row rank-4 reduce, C-folded ----------
// lows[row][0..3] = lq = x.Aq^T ; lows[row][4..7] = lv = x.Av^T + 2*lq.C^T
__global__ void __launch_bounds__(THREADS, 6) lora_reduce_kernel(
    const float* __restrict__ x,
    const float* __restrict__ A_q, const float* __restrict__ A_v,
    const float* __restrict__ C,
    float* __restrict__ lows)
{
    const int tid = threadIdx.x;
    const size_t row0 = (size_t)blockIdx.x * 4;
    const float* xbase = x + row0 * H;

    float accq[4][4], accv[4][4];
#pragma unroll
    for (int m = 0; m < 4; ++m)
#pragma unroll
        for (int r = 0; r < 4; ++r) { accq[m][r] = 0.f; accv[m][r] = 0.f; }

    // Staggered chunk order: decorrelate which A lines concurrent blocks hit.
#pragma unroll
    for (int cc = 0; cc < 4; ++cc) {
        const int c = (cc + (int)blockIdx.x) & 3;
        const int d0 = c * (THREADS * 4) + tid * 4;
        float4 xv[4];
#pragma unroll
        for (int m = 0; m < 4; ++m)
            xv[m] = *reinterpret_cast<const float4*>(xbase + (size_t)m * H + d0);
#pragma unroll
        for (int r = 0; r < 4; ++r) {
            float4 aq = *reinterpret_cast<const float4*>(A_q + (size_t)r * H + d0);
#pragma unroll
            for (int m = 0; m < 4; ++m) accq[m][r] += dot4(xv[m], aq);
        }
#pragma unroll
        for (int r = 0; r < 4; ++r) {
            float4 av = *reinterpret_cast<const float4*>(A_v + (size_t)r * H + d0);
#pragma unroll
            for (int m = 0; m < 4; ++m) accv[m][r] += dot4(xv[m], av);
        }
    }

    // Block-reduce 32 values: idx = m*8 + v  (v<4: accq, v>=4: accv)
    const int lane = tid & 63, wave = tid >> 6;
    __shared__ float red[4][32];
    __shared__ float sums[32];
#pragma unroll
    for (int i = 0; i < 32; ++i) {
        const int m = i >> 3, v = i & 7;
        float s = (v < 4) ? accq[m][v] : accv[m][v - 4];
#pragma unroll
        for (int off = 1; off < 64; off <<= 1) s += __shfl_xor(s, off, 64);
        if (lane == 0) red[wave][i] = s;
    }
    __syncthreads();
    if (tid < 32) sums[tid] = red[0][tid] + red[1][tid] + red[2][tid] + red[3][tid];
    __syncthreads();
    if (tid < 32) {
        const int m = tid >> 3, v = tid & 7;
        float val = sums[tid];
        if (v >= 4) {
            const int rp = v - 4;
#pragma unroll
            for (int r = 0; r < 4; ++r)
                val += 2.f * sums[m * 8 + r] * C[rp * 4 + r];
        }
        lows[(row0 + m) * 8 + v] = val;
    }
}

// ---------- kernel 2: d-sliced apply ----------
// Block = (slice of 1024 d's) x (16 rows). B slice lives in registers,
// loaded once per block: per-row shared-operand traffic is ~32B (uniform).
__global__ void __launch_bounds__(THREADS, 6) lora_apply_kernel(
    const float* __restrict__ x,
    const float* __restrict__ B_q, const float* __restrict__ B_v,
    const float* __restrict__ lows,
    float* __restrict__ out)
{
    const int tid = threadIdx.x;
    const int slice = blockIdx.x & 3;          // H / (THREADS*4) = 4 slices
    const int grp = blockIdx.x >> 2;           // row group of 16
    const int d = slice * (THREADS * 4) + tid * 4;

    // B fragments for this thread's 4 d's, pre-scaled by 2 (the LoRA scaling).
    float4 bq[4], bv[4];
#pragma unroll
    for (int i = 0; i < 4; ++i) {
        float4 t = *reinterpret_cast<const float4*>(B_q + (size_t)(d + i) * 4);
        bq[i] = make_float4(2.f * t.x, 2.f * t.y, 2.f * t.z, 2.f * t.w);
        float4 u = *reinterpret_cast<const float4*>(B_v + (size_t)(d + i) * 4);
        bv[i] = make_float4(2.f * u.x, 2.f * u.y, 2.f * u.z, 2.f * u.w);
    }

    const size_t row0 = (size_t)grp * 16;
#pragma unroll 2
    for (int j = 0; j < 16; ++j) {
        const size_t row = row0 + j;
        // Uniform per-row loads (same address across threads -> scalar path).
        const float4 lq = *reinterpret_cast<const float4*>(lows + row * 8);
        const float4 lv = *reinterpret_cast<const float4*>(lows + row * 8 + 4);
        const float4 xv = *reinterpret_cast<const float4*>(x + row * H + d);
        float4 o;
        o.x = 2.f * xv.x + lq.x * bq[0].x + lq.y * bq[0].y + lq.z * bq[0].z + lq.w * bq[0].w
                         + lv.x * bv[0].x + lv.y * bv[0].y + lv.z * bv[0].z + lv.w * bv[0].w;
        o.y = 2.f * xv.y + lq.x * bq[1].x + lq.y * bq[1].y + lq.z * bq[1].z + lq.w * bq[1].w
                         + lv.x * bv[1].x + lv.y * bv[1].y + lv.z * bv[1].z + lv.w * bv[1].w;
        o.z = 2.f * xv.z + lq.x * bq[2].x + lq.y * bq[2].y + lq.z * bq[2].z + lq.w * bq[2].w
                         + lv.x * bv[2].x + lv.y * bv[2].y + lv.z * bv[2].z + lv.w * bv[2].w;
        o.w = 2.f * xv.w + lq.x * bq[3].x + lq.y * bq[3].y + lq.z * bq[3].z + lq.w * bq[3].w
                         + lv.x * bv[3].x + lv.y * bv[3].y + lv.z * bv[3].z + lv.w * bv[3].w;
        *reinterpret_cast<float4*>(out + row * H + d) = o;
    }
}

extern "C" void kernel_launch(void* const* d_in, const int* in_sizes, int n_in,
                              void* d_out, int out_size, void* d_ws, size_t ws_size,
                              hipStream_t stream) {
    const float* x   = (const float*)d_in[0];
    const float* A_q = (const float*)d_in[1];
    const float* B_q = (const float*)d_in[2];
    const float* A_v = (const float*)d_in[3];
    const float* B_v = (const float*)d_in[4];
    float* out  = (float*)d_out;
    float* C    = (float*)d_ws;                 // 16 floats
    float* lows = (float*)d_ws + 16;            // nrows*8 floats (256 KB)

    const int nrows = in_sizes[0] / H;          // B*S = 8192

    compute_C_kernel<<<1, THREADS, 0, stream>>>(A_v, B_q, C);
    lora_reduce_kernel<<<nrows / 4, THREADS, 0, stream>>>(x, A_q, A_v, C, lows);
    lora_apply_kernel<<<4 * (nrows / 16), THREADS, 0, stream>>>(x, B_q, B_v, lows, out);
}